// Round 16
// baseline (107.491 us; speedup 1.0000x reference)
//
#include <hip/hip_runtime.h>

// LogicConv3d: B=4, C=3, H=W=D=32, K=32, S=16 leaves, tree depth 4 (31 LUT nodes).
// Out: (B, K, 30, 30, 30) = 3,456,000 fp32.
//
// R15: DIAGNOSTIC round. Exactly R10 (best: split gathers, A-leaves from fp32
// LDS slab, B-leaves from global; 8-od octets; fused L0+1; bounds(256,3)) with
// the eval+store wrapped in a 3x repeat loop. Addresses depend on rep*rep_off
// where rep_off is an OPAQUE runtime kernel arg (=0), so codegen must fully
// re-execute each rep; reps write identical values to identical addresses ->
// output unchanged. Purpose: the kernel has been faster than the 40us harness
// fills since R4 and invisible to the top-5 counter table — tripling its
// duration (~72us) surfaces VALUBusy / LDS_BANK_CONFLICT / FETCH / occupancy
// so the next change is evidence-driven instead of the 5th blind guess.

#define B_  4
#define C_  3
#define H_  32
#define W_  32
#define D_  32
#define K_  32
#define S_  16
#define WS  33      // padded d-row stride (dwords); %32==1 rotates banks per ow
#define TPB 256
#define CHWD (C_ * H_ * W_ * D_)

typedef float v8f __attribute__((ext_vector_type(8)));
typedef float f8a __attribute__((ext_vector_type(8), aligned(4)));
typedef float f4a __attribute__((ext_vector_type(4), aligned(4)));
typedef float f2a __attribute__((ext_vector_type(2), aligned(4)));

__device__ __forceinline__ v8f lut8(v8f a, v8f b, float l0, float d1, float d2, float d3) {
    // E = l0 + a*d2 + b*d1 + (a*b)*d3 == fma(b, fma(a,d3,d1), fma(a,d2,l0))
    const v8f t0 = a * d2 + l0;
    const v8f t1 = a * d3 + d1;
    return b * t1 + t0;
}

__global__ __launch_bounds__(TPB, 3) void logic_conv3d(
    const float* __restrict__ x,
    const int*   __restrict__ kc,
    const float* __restrict__ w0,
    const float* __restrict__ w1,
    const float* __restrict__ w2,
    const float* __restrict__ w3,
    const float* __restrict__ w4,
    float*       __restrict__ out,
    int rep_off)                     // == 0 at runtime; opaque to codegen
{
    __shared__ float4 s_lut[31];     // (l0, d1, d2, d3) per node
    __shared__ int    s_lb[16];      // A-leaf base, fp32 slab coords
    __shared__ int    s_gb[16];      // B-leaf base, global dword coords
    __shared__ __align__(16) float slab[12 * 32 * WS + 8];  // 50.7 KB + pad

    const int bk  = blockIdx.x;      // b*K + k
    const int b   = bk >> 5;
    const int k   = bk & 31;
    const int tid = threadIdx.x;

    // ---- per-block setup: 31 softmax->LUT (delta form) + leaf bases ----
    if (tid < 31) {
        const float* wp; int ln;
        if      (tid < 16) { wp = w0; ln = tid;      }
        else if (tid < 24) { wp = w1; ln = tid - 16; }
        else if (tid < 28) { wp = w2; ln = tid - 24; }
        else if (tid < 30) { wp = w3; ln = tid - 28; }
        else               { wp = w4; ln = 0;        }
        const float* wrow = wp + (ln * K_ + k) * 16;
        float lg[16];
        float m = -1e30f;
        #pragma unroll
        for (int g = 0; g < 16; ++g) { lg[g] = wrow[g]; m = fmaxf(m, lg[g]); }
        float z = 0.f;
        #pragma unroll
        for (int g = 0; g < 16; ++g) { lg[g] = __expf(lg[g] - m); z += lg[g]; }
        const float inv = 1.0f / z;
        float l0 = 0.f, l1 = 0.f, l2 = 0.f, l3 = 0.f;
        #pragma unroll
        for (int g = 0; g < 16; ++g) {
            float p = lg[g] * inv;           // GATES[g,t] = (g>>t)&1, t = 2*a+b
            if (g & 1) l0 += p;
            if (g & 2) l1 += p;
            if (g & 4) l2 += p;
            if (g & 8) l3 += p;
        }
        s_lut[tid] = make_float4(l0, l1 - l0, l2 - l0, (l3 - l2) - (l1 - l0));
    } else if (tid >= 32 && tid < 64) {
        const int idx  = tid - 32;           // tree*16 + s
        const int tree = idx >> 4;
        const int s    = idx & 15;
        const int off  = ((tree * K_ + k) * S_ + s) * 4;  // kc (2,K,S,4) = (h,w,d,c)
        const int h = kc[off + 0], w = kc[off + 1], d = kc[off + 2], c = kc[off + 3];
        if (tree == 0)
            s_lb[s] = ((c * 4 + h) * 32 + w) * WS + d;        // slab coords
        else
            s_gb[s] = ((c * H_ + h) * W_ + w) * D_ + d;       // global coords
    }

    // ---- stage fp32 slab: 12 planes (3c x 4h) of 32x32 dwords, coalesced ----
    {
        const float* xb = x + (size_t)b * CHWD + (blockIdx.y * 2) * (W_ * D_);
        const int w  = tid >> 3;             // 0..31
        const int d4 = (tid & 7) << 2;       // 0,4,...,28
        #pragma unroll
        for (int it = 0; it < 12; ++it) {
            const int c  = it >> 2;          // 0..2
            const int dh = it & 3;           // 0..3
            const float4 val = *(const float4*)(xb + c * (H_ * W_ * D_) + dh * (W_ * D_) + tid * 4);
            *(float4*)&slab[((c * 4 + dh) * 32 + w) * WS + d4] = val;
        }
    }
    __syncthreads();

    // ---- bases -> SGPRs (aligned b128 + readfirstlane) ----
    int sA[16], sB[16];
    #pragma unroll
    for (int i = 0; i < 4; ++i) {
        const int4 qa = *(const int4*)&s_lb[i * 4];
        sA[i * 4 + 0] = __builtin_amdgcn_readfirstlane(qa.x);
        sA[i * 4 + 1] = __builtin_amdgcn_readfirstlane(qa.y);
        sA[i * 4 + 2] = __builtin_amdgcn_readfirstlane(qa.z);
        sA[i * 4 + 3] = __builtin_amdgcn_readfirstlane(qa.w);
        const int4 qb = *(const int4*)&s_gb[i * 4];
        sB[i * 4 + 0] = __builtin_amdgcn_readfirstlane(qb.x);
        sB[i * 4 + 1] = __builtin_amdgcn_readfirstlane(qb.y);
        sB[i * 4 + 2] = __builtin_amdgcn_readfirstlane(qb.z);
        sB[i * 4 + 3] = __builtin_amdgcn_readfirstlane(qb.w);
    }

    // thread -> (oh_local, ow, octet of consecutive od)
    const int ohl = tid >> 7;                // 0,1
    const int r   = tid & 127;
    const int ow  = r >> 2;                  // 0..31 (>=30 inactive)
    const int gq  = r & 3;                   // 0..3
    const int od0 = gq << 3;                 // 0,8,16,24 (od 30/31 dropped)

    if (ow < 30) {
        const int oh  = blockIdx.y * 2 + ohl;
        const int vs0 = ohl * (32 * WS) + ow * WS + od0;            // slab offset
        const int vg0 = b * CHWD + oh * (W_ * D_) + ow * D_ + od0;  // global offset

        // === diagnostic repeat: rep_off == 0, so all reps do identical work ===
        for (int rep = 0; rep < 3; ++rep) {
            const int vs = vs0 + rep * rep_off;
            const int vg = vg0 + rep * rep_off;

            // ---- fused levels 0+1: leaf pair -> level-1 node ----
            v8f v1[8];
            #pragma unroll
            for (int j = 0; j < 8; ++j) {
                const int s0 = 2 * j, s1 = 2 * j + 1;
                const v8f A0 = (v8f)(*(const f8a*)&slab[sA[s0] + vs]);
                const v8f B0 = (v8f)(*(const f8a*)(x + sB[s0] + vg));
                const float4 L0 = s_lut[s0];
                const v8f t0 = lut8(A0, B0, L0.x, L0.y, L0.z, L0.w);
                const v8f A1 = (v8f)(*(const f8a*)&slab[sA[s1] + vs]);
                const v8f B1 = (v8f)(*(const f8a*)(x + sB[s1] + vg));
                const float4 L1 = s_lut[s1];
                const v8f t1 = lut8(A1, B1, L1.x, L1.y, L1.z, L1.w);
                const float4 LN = s_lut[16 + j];
                v1[j] = lut8(t0, t1, LN.x, LN.y, LN.z, LN.w);
            }

            // ---- levels 2..4 ----
            #pragma unroll
            for (int j = 0; j < 4; ++j) {
                const float4 L = s_lut[24 + j];
                v1[j] = lut8(v1[2 * j], v1[2 * j + 1], L.x, L.y, L.z, L.w);
            }
            #pragma unroll
            for (int j = 0; j < 2; ++j) {
                const float4 L = s_lut[28 + j];
                v1[j] = lut8(v1[2 * j], v1[2 * j + 1], L.x, L.y, L.z, L.w);
            }
            const float4 Pr = s_lut[30];
            v1[0] = lut8(v1[0], v1[1], Pr.x, Pr.y, Pr.z, Pr.w);

            // store: full octet for gq<3; od 24..29 only for gq==3
            float* outp = out + (size_t)bk * 27000 + oh * 900 + ow * 30 + od0
                              + rep * rep_off;
            f4a lo; lo[0] = v1[0][0]; lo[1] = v1[0][1]; lo[2] = v1[0][2]; lo[3] = v1[0][3];
            *(f4a*)outp = lo;
            if (gq < 3) {
                f4a hi; hi[0] = v1[0][4]; hi[1] = v1[0][5]; hi[2] = v1[0][6]; hi[3] = v1[0][7];
                *(f4a*)(outp + 4) = hi;
            } else {
                f2a hi2; hi2[0] = v1[0][4]; hi2[1] = v1[0][5];
                *(f2a*)(outp + 4) = hi2;
            }
        }
    }
}

extern "C" void kernel_launch(void* const* d_in, const int* in_sizes, int n_in,
                              void* d_out, int out_size, void* d_ws, size_t ws_size,
                              hipStream_t stream) {
    const float* x  = (const float*)d_in[0];
    const int*   kc = (const int*)d_in[1];
    const float* w0 = (const float*)d_in[2];
    const float* w1 = (const float*)d_in[3];
    const float* w2 = (const float*)d_in[4];
    const float* w3 = (const float*)d_in[5];
    const float* w4 = (const float*)d_in[6];
    float* out = (float*)d_out;

    dim3 grid(B_ * K_, 15);  // (bk, oh-pair) = 1920 blocks
    logic_conv3d<<<grid, TPB, 0, stream>>>(x, kc, w0, w1, w2, w3, w4, out, 0);
}